// Round 1
// 176.618 us; speedup vs baseline: 1.0508x; 1.0508x over previous
//
#include <hip/hip_runtime.h>
#include <hip/hip_bf16.h>
#include <cstdint>

// ---------------------------------------------------------------------------
// CausalSelfAttention: x@Wqkv+b -> heads -> causal flash attn -> @Wproj+b
// B=2 T=2048 C=1024 H=16 Dh=64.
// R11: gemm_qkv rewritten as the 256x256 8-phase counted-vmcnt template
// (T2 LDS XOR-swizzle + T3/T4 phase pipeline + T5 setprio), BK=64, 8 waves.
// Schedule per K-tile (4 phases x 16 MFMA):
//   p0: ds A(m0-3)+B(n0-1), stage Bhi(kt+1)->buf^1 | MFMA (lo,lo)
//   p1: ds B(n2-3)                                 | MFMA (lo,hi)
//   p2: ds A(m4-7), stage Blo(kt+2)->buf           | MFMA (hi,hi)
//   p3: stage Alo+Ahi(kt+2)->buf                   | MFMA (hi,lo); vmcnt(6)
// Region-overwrite safety: all B reads of buf complete by p1's barrier,
// all A reads by p2's barrier (each phase waits lgkmcnt(0) pre-barrier).
// vmcnt(6) leaves exactly kt+2's A+Blo (3 half-tiles) in flight - never a
// full drain in the main loop (T4).  Swizzle: LDS granule ^= row&7, with the
// inverse swizzle pre-applied to the per-lane GLOBAL source (linear
// global_load_lds dest - rule: both-sides-or-neither).
// HARD-WON NOTES (attn, unchanged):
//  - R7: __launch_bounds__(256,4) forced VGPR=64 -> 380MB scratch spills.
//  - R8: V-frag loads after softmax doubled per-tile exposed latency.
//  - R10: K-frags pipelined one tile ahead; ps tree-summed; l-reduction
//    deferred to epilogue.
// ---------------------------------------------------------------------------

using u16 = unsigned short;
using u32 = unsigned int;

typedef __bf16 bf16x8 __attribute__((ext_vector_type(8)));
typedef float f32x4 __attribute__((ext_vector_type(4)));

#define AS1 __attribute__((address_space(1)))
#define AS3 __attribute__((address_space(3)))

__device__ __forceinline__ u16 f2bf(float f) {
  u32 u = __float_as_uint(f);
  u += 0x7fffu + ((u >> 16) & 1u);   // RTNE
  return (u16)(u >> 16);
}
// pack two positive floats -> two bf16
__device__ __forceinline__ u32 pack2bf(float a, float b) {
  u32 ua = __float_as_uint(a) + 0x8000u;
  u32 ub = __float_as_uint(b) + 0x8000u;
  return (ua >> 16) | (ub & 0xffff0000u);
}

// ---------------- prep: cvt x->bf16 (blocks 0..4095) + W transposes ---------
__global__ __launch_bounds__(256) void prep(const float* __restrict__ x,
                                            u16* __restrict__ xb,
                                            const float* __restrict__ W0,
                                            u16* __restrict__ T0,
                                            const float* __restrict__ W1,
                                            u16* __restrict__ T1) {
  const int bx = blockIdx.x;
  const int tid = threadIdx.x;
  if (bx < 4096) {
    const int i = bx * 256 + tid;
    float4 v = ((const float4*)x)[i];
    ushort4 o;
    o.x = f2bf(v.x); o.y = f2bf(v.y); o.z = f2bf(v.z); o.w = f2bf(v.w);
    ((ushort4*)xb)[i] = o;
    return;
  }
  __shared__ float t[32][33];
  const int idx = bx - 4096;          // 128 n-tiles x 32 k-tiles
  const int bxx = idx & 127, by = idx >> 7;
  const float* W; u16* Wt; int N, n0;
  if (bxx < 96) { W = W0; Wt = T0; N = 3072; n0 = bxx * 32; }
  else          { W = W1; Wt = T1; N = 1024; n0 = (bxx - 96) * 32; }
  const int k0 = by * 32;
  const int tx = tid & 31, ty = tid >> 5;
#pragma unroll
  for (int i = 0; i < 4; ++i)
    t[ty + i * 8][tx] = W[(size_t)(k0 + ty + i * 8) * N + n0 + tx];
  __syncthreads();
#pragma unroll
  for (int i = 0; i < 4; ++i)
    Wt[(size_t)(n0 + ty + i * 8) * 1024 + k0 + tx] = f2bf(t[tx][ty + i * 8]);
}

// ---------------- QKV GEMM: 256x256 8-phase (m201 structure) ----------------
// n<1024: Q (scaled by cs) -> qb[4096][1024]
// 1024<=n<2048: K -> KF fragment order [bh][kt][m][hh][lane][8]
// n>=2048:     V -> VF fragment order [bh][kt][hh][di][lane][8] (k-permuted)
#define MFMA16 __builtin_amdgcn_mfma_f32_16x16x32_bf16

__global__ __launch_bounds__(512, 2) void gemm_qkv(const u16* __restrict__ A,
                                                   const u16* __restrict__ Bt,
                                                   const float* __restrict__ bias,
                                                   u16* __restrict__ qb,
                                                   u16* __restrict__ KF,
                                                   u16* __restrict__ VF,
                                                   float sc_val) {
  constexpr int NT = 16;                         // K=1024 / BK=64
  __shared__ __align__(16) u16 sm[2 * 4 * 8192]; // 128 KiB: [buf][reg][128][64]
  // regions: 0=A-lo 1=A-hi 2=B-lo 3=B-hi (each 128 rows x 64 cols bf16)

  const int tid  = threadIdx.x;
  const int lane = tid & 63;
  const int w    = tid >> 6;          // 0..7
  const int quad = lane >> 4;
  const int l15  = lane & 15;

  // block -> tile: XCD-bijective (192 blocks = 8 XCD x 24), 4x6 region/XCD
  const int bid = blockIdx.x;
  const int xcd = bid & 7, c = bid >> 3;
  const int mt = (xcd >> 1) * 4 + (c & 3);       // 0..15
  const int nt = (xcd & 1) * 6 + (c >> 2);       // 0..11
  const int bm = mt * 256, bn = nt * 256;

  const int wr = (w >> 2) * 128;      // wave output rows
  const int wc = (w & 3) * 64;        // wave output cols

  // ---- staging constants: lane writes LDS linear chunk (w+i*8)*1KB+lane*16.
  // LDS row = w*8 + i*64 + (lane>>3); granule(lane&7) holds global granule
  // (lane&7)^(row&7); row&7 == lane>>3 for all regions/halves.
  const int rowS = w * 8 + (lane >> 3);              // region-local row, i=0
  const int scol = (((lane & 7) ^ (lane >> 3)) << 3);// pre-swizzled col (elems)

#define STAGE(matp, rowbase, ldsoff, ktile)                                     \
  do {                                                                          \
    const u16* _s = (matp) + ((size_t)((rowbase) + rowS) << 10) +               \
                    ((ktile) << 6) + scol;                                      \
    u16* _d = sm + (ldsoff) + (w << 9);                                         \
    __builtin_amdgcn_global_load_lds((AS1 const void*)_s, (AS3 void*)_d,        \
                                     16, 0, 0);                                 \
    __builtin_amdgcn_global_load_lds((AS1 const void*)(_s + (64 << 10)),        \
                                     (AS3 void*)(_d + 4096), 16, 0, 0);         \
  } while (0)

  // ---- ds-read constants (swizzled granule): row r=mi*16+l15 -> r&7=l15&7
  const int raoff = (wr >> 7) * 8192;        // this wave's A region
  const int rboff = (2 + (wc >> 7)) * 8192;  // this wave's B region
  const int av0 = l15 * 64 + ((quad ^ (l15 & 7)) << 3);         // ks=0
  const int av1 = l15 * 64 + (((4 + quad) ^ (l15 & 7)) << 3);   // ks=1
  const int bv0 = ((wc & 64) + l15) * 64 + ((quad ^ (l15 & 7)) << 3);
  const int bv1 = ((wc & 64) + l15) * 64 + (((4 + quad) ^ (l15 & 7)) << 3);

  // ---- prologue: kt0 all 4 halves -> buf0; kt1 Blo,Alo,Ahi -> buf1
  STAGE(A,  bm,       0 * 8192, 0);
  STAGE(A,  bm + 128, 1 * 8192, 0);
  STAGE(Bt, bn,       2 * 8192, 0);
  STAGE(Bt, bn + 128, 3 * 8192, 0);
  STAGE(Bt, bn,       32768 + 2 * 8192, 1);
  STAGE(A,  bm,       32768 + 0 * 8192, 1);
  STAGE(A,  bm + 128, 32768 + 1 * 8192, 1);
  asm volatile("s_waitcnt vmcnt(6)" ::: "memory");  // kt0 landed; 6 in flight
  __builtin_amdgcn_s_barrier();

  f32x4 acc[8][4] = {};
  bf16x8 a[4][2], b[4][2];

#pragma unroll 2
  for (int kt = 0; kt < NT; ++kt) {
    const int bo  = (kt & 1) * 32768;
    const int nbo = bo ^ 32768;
    const u16* smA = sm + bo + raoff;
    const u16* smB = sm + bo + rboff;

    // ---------- phase 0: ds A m0-3 + B n0-1; stage Bhi(kt+1); MFMA (lo,lo)
#pragma unroll
    for (int mi = 0; mi < 4; ++mi) {
      a[mi][0] = *(const bf16x8*)(smA + mi * 1024 + av0);
      a[mi][1] = *(const bf16x8*)(smA + mi * 1024 + av1);
    }
#pragma unroll
    for (int ni = 0; ni < 2; ++ni) {
      b[ni][0] = *(const bf16x8*)(smB + ni * 1024 + bv0);
      b[ni][1] = *(const bf16x8*)(smB + ni * 1024 + bv1);
    }
    if (kt + 1 < NT) STAGE(Bt, bn + 128, nbo + 3 * 8192, kt + 1);
    __builtin_amdgcn_s_barrier();
    asm volatile("s_waitcnt lgkmcnt(0)" ::: "memory");
    __builtin_amdgcn_s_setprio(1);
#pragma unroll
    for (int mi = 0; mi < 4; ++mi)
#pragma unroll
      for (int ni = 0; ni < 2; ++ni) {
        acc[mi][ni] = MFMA16(a[mi][0], b[ni][0], acc[mi][ni], 0, 0, 0);
        acc[mi][ni] = MFMA16(a[mi][1], b[ni][1], acc[mi][ni], 0, 0, 0);
      }
    __builtin_amdgcn_s_setprio(0);
    __builtin_amdgcn_s_barrier();

    // ---------- phase 1: ds B n2-3; MFMA (lo,hi)
#pragma unroll
    for (int ni = 2; ni < 4; ++ni) {
      b[ni][0] = *(const bf16x8*)(smB + ni * 1024 + bv0);
      b[ni][1] = *(const bf16x8*)(smB + ni * 1024 + bv1);
    }
    __builtin_amdgcn_s_barrier();
    asm volatile("s_waitcnt lgkmcnt(0)" ::: "memory");
    __builtin_amdgcn_s_setprio(1);
#pragma unroll
    for (int mi = 0; mi < 4; ++mi)
#pragma unroll
      for (int ni = 2; ni < 4; ++ni) {
        acc[mi][ni] = MFMA16(a[mi][0], b[ni][0], acc[mi][ni], 0, 0, 0);
        acc[mi][ni] = MFMA16(a[mi][1], b[ni][1], acc[mi][ni], 0, 0, 0);
      }
    __builtin_amdgcn_s_setprio(0);
    __builtin_amdgcn_s_barrier();
    // all B reads of buf complete here (p0+p1 lgkm'd pre-barrier)

    // ---------- phase 2: ds A m4-7; stage Blo(kt+2)->buf; MFMA (hi,hi)
#pragma unroll
    for (int mi = 0; mi < 4; ++mi) {
      a[mi][0] = *(const bf16x8*)(smA + (4 + mi) * 1024 + av0);
      a[mi][1] = *(const bf16x8*)(smA + (4 + mi) * 1024 + av1);
    }
    if (kt + 2 < NT) STAGE(Bt, bn, bo + 2 * 8192, kt + 2);
    __builtin_amdgcn_s_barrier();
    asm volatile("s_waitcnt lgkmcnt(0)" ::: "memory");
    __builtin_amdgcn_s_setprio(1);
#pragma unroll
    for (int mi = 0; mi < 4; ++mi)
#pragma unroll
      for (int ni = 2; ni < 4; ++ni) {
        acc[4 + mi][ni] = MFMA16(a[mi][0], b[ni][0], acc[4 + mi][ni], 0, 0, 0);
        acc[4 + mi][ni] = MFMA16(a[mi][1], b[ni][1], acc[4 + mi][ni], 0, 0, 0);
      }
    __builtin_amdgcn_s_setprio(0);
    __builtin_amdgcn_s_barrier();
    // all A reads of buf complete here

    // ---------- phase 3: stage Alo+Ahi(kt+2)->buf; MFMA (hi,lo); vmcnt(6)
    if (kt + 2 < NT) {
      STAGE(A, bm,       bo + 0 * 8192, kt + 2);
      STAGE(A, bm + 128, bo + 1 * 8192, kt + 2);
    }
    __builtin_amdgcn_s_barrier();
    __builtin_amdgcn_s_setprio(1);
#pragma unroll
    for (int mi = 0; mi < 4; ++mi)
#pragma unroll
      for (int ni = 0; ni < 2; ++ni) {
        acc[4 + mi][ni] = MFMA16(a[mi][0], b[ni][0], acc[4 + mi][ni], 0, 0, 0);
        acc[4 + mi][ni] = MFMA16(a[mi][1], b[ni][1], acc[4 + mi][ni], 0, 0, 0);
      }
    __builtin_amdgcn_s_setprio(0);
    if (kt + 2 < NT)
      asm volatile("s_waitcnt vmcnt(6)" ::: "memory"); // kt+1 landed, 6 fly
    else
      asm volatile("s_waitcnt vmcnt(0)" ::: "memory"); // tail drain
    __builtin_amdgcn_s_barrier();
  }
#undef STAGE

  // ---- epilogue (same index math as 128^2 version; mi now 0..7) ----
  const int crow0 = bm + wr + (quad << 2);
  const int ccol0 = bn + wc + l15;
  if (bn < 1024) {                      // ---- Q (scaled) ----
#pragma unroll
    for (int ni = 0; ni < 4; ++ni) {
      const int n = ccol0 + ni * 16;
      const float bv = bias[n];
#pragma unroll
      for (int mi = 0; mi < 8; ++mi) {
        const int m0 = crow0 + mi * 16;
#pragma unroll
        for (int r = 0; r < 4; ++r)
          qb[(size_t)(m0 + r) * 1024 + n] = f2bf((acc[mi][ni][r] + bv) * sc_val);
      }
    }
  } else if (bn < 2048) {               // ---- K fragment order ----
#pragma unroll
    for (int ni = 0; ni < 4; ++ni) {
      const int n  = ccol0 + ni * 16;
      const int hk = (n - 1024) >> 6;
      const int d  = (n - 1024) & 63;
      const int hh = d >> 5, qd = (d >> 3) & 3, j = d & 7;
      const float bv = bias[n];
#pragma unroll
      for (int mi = 0; mi < 8; ++mi) {
#pragma unroll
        for (int r = 0; r < 4; ++r) {
          const int t  = crow0 + mi * 16 + r;
          const int bb = t >> 11, tt = t & 2047;
          const int kt = tt >> 6, mm = (tt >> 4) & 3, l = tt & 15;
          KF[((size_t)((bb * 16 + hk) * 32 + kt) * 8 + mm * 2 + hh) * 512 +
             (qd * 16 + l) * 8 + j] = f2bf(acc[mi][ni][r] + bv);
        }
      }
    }
  } else {                              // ---- V fragment order (k-perm) ----
#pragma unroll
    for (int ni = 0; ni < 4; ++ni) {
      const int n  = ccol0 + ni * 16;
      const int hv = (n - 2048) >> 6;
      const int d  = (n - 2048) & 63;
      const int di = d >> 4, l = d & 15;
      const float bv = bias[n];
#pragma unroll
      for (int mi = 0; mi < 8; ++mi) {
#pragma unroll
        for (int r = 0; r < 4; ++r) {
          const int t  = crow0 + mi * 16 + r;
          const int bb = t >> 11, tt = t & 2047;
          const int kt = tt >> 6, to = tt & 63;
          const int mq = to >> 4, qd2 = (to >> 2) & 3, rr = to & 3;
          const int hh = mq >> 1, j = (mq & 1) * 4 + rr;
          VF[((size_t)((bb * 16 + hv) * 32 + kt) * 8 + hh * 4 + di) * 512 +
             (qd2 * 16 + l) * 8 + j] = f2bf(acc[mi][ni][r] + bv);
        }
      }
    }
  }
}

// ---------------- Proj GEMM: 128x64 tile, fp32 out --------------------------
__global__ __launch_bounds__(256) void gemm_proj(const u16* __restrict__ A,
                                                 const u16* __restrict__ Bt,
                                                 const float* __restrict__ bias,
                                                 float* __restrict__ C) {
  constexpr int BM = 128, BN = 64, BK = 32;
  constexpr int K = 1024, N = 1024;
  __shared__ __align__(16) u16 lA[BM * BK];
  __shared__ __align__(16) u16 lB[BN * BK];
  const int tid  = threadIdx.x;
  const int lane = tid & 63;
  const int wave = tid >> 6;
  const int bm = blockIdx.x * BM;
  const int bn = blockIdx.y * BN;
  const int wr = wave * 32;

  f32x4 acc[2][4] = {};

  const int f0 = (wave << 10) + (lane << 4);
  const int f1 = f0 + 4096;
  const int ar0 = f0 >> 6, ac0 = (f0 & 63) >> 1;
  const int ar1 = f1 >> 6, ac1 = (f1 & 63) >> 1;

  const int arow = wr + (lane & 15);
  const int brow = (lane & 15);
  const int kk   = (lane >> 4) << 3;

  for (int k0 = 0; k0 < K; k0 += BK) {
    __builtin_amdgcn_global_load_lds((AS1 const void*)(A + (size_t)(bm + ar0) * K + k0 + ac0),
                                     (AS3 void*)(lA + (wave << 9)), 16, 0, 0);
    __builtin_amdgcn_global_load_lds((AS1 const void*)(A + (size_t)(bm + ar1) * K + k0 + ac1),
                                     (AS3 void*)(lA + ((wave + 4) << 9)), 16, 0, 0);
    __builtin_amdgcn_global_load_lds((AS1 const void*)(Bt + (size_t)(bn + ar0) * K + k0 + ac0),
                                     (AS3 void*)(lB + (wave << 9)), 16, 0, 0);
    __syncthreads();

    bf16x8 af[2], bfr[4];
#pragma unroll
    for (int mi = 0; mi < 2; ++mi)
      af[mi] = *(const bf16x8*)&lA[(arow + mi * 16) * BK + kk];
#pragma unroll
    for (int ni = 0; ni < 4; ++ni)
      bfr[ni] = *(const bf16x8*)&lB[(brow + ni * 16) * BK + kk];
#pragma unroll
    for (int mi = 0; mi < 2; ++mi)
#pragma unroll
      for (int ni = 0; ni < 4; ++ni)
        acc[mi][ni] = __builtin_amdgcn_mfma_f32_16x16x32_bf16(af[mi], bfr[ni],
                                                              acc[mi][ni], 0, 0, 0);
    __syncthreads();
  }

  const int crow0 = bm + wr + ((lane >> 4) << 2);
  const int ccol0 = bn + (lane & 15);
#pragma unroll
  for (int ni = 0; ni < 4; ++ni) {
    const int n = ccol0 + ni * 16;
    const float bv = bias[n];
#pragma unroll
    for (int mi = 0; mi < 2; ++mi) {
      const int m0 = crow0 + mi * 16;
#pragma unroll
      for (int r = 0; r < 4; ++r)
        C[(size_t)(m0 + r) * N + n] = acc[mi][ni][r] + bv;
    }
  }
}

// ---------------- balanced pipelined MFMA flash attention -------------------
// grid (32 u, 32 bh); block 256 = 4 waves.
// wave w: g32 = (w&1) ? 63-u : u, par = w>>1; kt = par, par+2, ... <= ktmax.
// Per tile: V-frags load at top; K-frags for kt+2 load right after (depth-2
// pipeline, K used one full tile after issue).  Softmax: tree-summed ps,
// per-lane l accumulation (cross-lane reduction deferred to epilogue).
__global__ __launch_bounds__(256) void attn_bal(const u16* __restrict__ qb,
                                                const u16* __restrict__ KF,
                                                const u16* __restrict__ VF,
                                                u16* __restrict__ out) {
  const int u  = blockIdx.x;
  const int bh = blockIdx.y;
  const int b = bh >> 4, h = bh & 15;
  const int tid = threadIdx.x;
  const int lane = tid & 63;
  const int w    = tid >> 6;
  const int quad = lane >> 4;
  const int l15  = lane & 15;
  const int g32 = (w & 1) ? (63 - u) : u;
  const int par = w >> 1;
  const int q0 = g32 * 32;
  const int ktmax = g32 >> 1;

  __shared__ float CB[2][64][35];     // [unit][lane][32 accO + 2 lsum]

  // Q B-frags, held all kernel
  const u16* qbase = qb + (size_t)b * 2048 * 1024 + h * 64;
  bf16x8 qf[2][2];
#pragma unroll
  for (int g = 0; g < 2; ++g)
#pragma unroll
    for (int hh = 0; hh < 2; ++hh)
      qf[g][hh] = *(const bf16x8*)(qbase + (size_t)(q0 + g * 16 + l15) * 1024 +
                                   hh * 32 + quad * 8);

  const size_t fb = (size_t)bh * 32 * 4096 + lane * 8;
  const u16* kfb = KF + fb;
  const u16* vfb = VF + fb;

  f32x4 accO[2][4] = {};              // [g][di]: q=quad*4+r, d=di*16+l15
  float lrow[2] = {0.f, 0.f};         // PER-LANE partials; reduced in epilogue

  // prologue: K-frags for first tile
  bf16x8 kcur[4][2];
  {
    const u16* kp = kfb + (size_t)par * 4096;
#pragma unroll
    for (int m = 0; m < 4; ++m)
#pragma unroll
      for (int hh = 0; hh < 2; ++hh)
        kcur[m][hh] = *(const bf16x8*)(kp + (m * 2 + hh) * 512);
  }

  for (int kt = par; kt <= ktmax; kt += 2) {
    // V-frags for current tile at top
    const u16* vp = vfb + (size_t)kt * 4096;
    bf16x8 vfr[2][4];
#pragma unroll
    for (int hh = 0; hh < 2; ++hh)
#pragma unroll
      for (int di = 0; di < 4; ++di)
        vfr[hh][di] = *(const bf16x8*)(vp + (hh * 4 + di) * 512);
    // K-frags for tile kt+2 (clamped) -- used NEXT iteration
    const int ktn = (kt + 2 <= ktmax) ? kt + 2 : ktmax;
    const u16* kpn = kfb + (size_t)ktn * 4096;
    bf16x8 knx[4][2];
#pragma unroll
    for (int m = 0; m < 4; ++m)
#pragma unroll
      for (int hh = 0; hh < 2; ++hh)
        knx[m][hh] = *(const bf16x8*)(kpn + (m * 2 + hh) * 512);

    const bool diag = (kt == ktmax);
    bf16x8 ap[2][2];
#pragma unroll
    for (int g = 0; g < 2; ++g) {
      f32x4 sT[4] = {};
#pragma unroll
      for (int m = 0; m < 4; ++m) {
        sT[m] = __builtin_amdgcn_mfma_f32_16x16x32_bf16(kcur[m][0], qf[g][0], sT[m], 0, 0, 0);
        sT[m] = __builtin_amdgcn_mfma_f32_16x16x32_bf16(kcur[m][1], qf[g][1], sT[m], 0, 0, 0);
      }
      float pv[4][4];
      if (diag) {                      // only the last tile pays mask ops
        const int qgl = q0 + g * 16 + l15;
#pragma unroll
        for (int m = 0; m < 4; ++m)
#pragma unroll
          for (int r = 0; r < 4; ++r) {
            const bool msk = (kt * 64 + m * 16 + quad * 4 + r) > qgl;
            pv[m][r] = msk ? 0.f : __builtin_amdgcn_exp2f(sT[m][r]);
          }
      } else {
#pragma unroll
        for (int m = 0; m < 4; ++m)
#pragma unroll
          for (int r = 0; r < 4; ++r)
            pv[m][r] = __builtin_amdgcn_exp2f(sT[m][r]);
      }
      // tree sum (fp adds not reassociable by compiler -- do it manually)
      const float s0 = (pv[0][0] + pv[0][1]) + (pv[0][2] + pv[0][3]);
      const float s1 = (pv[1][0] + pv[1][1]) + (pv[1][2] + pv[1][3]);
      const float s2 = (pv[2][0] + pv[2][1]) + (pv[2][2] + pv[2][3]);
      const float s3 = (pv[3][0] + pv[3][1]) + (pv[3][2] + pv[3][3]);
      lrow[g] += (s0 + s1) + (s2 + s3);

      union { u32 u4[4]; bf16x8 v; } t0, t1;
      t0.u4[0] = pack2bf(pv[0][0], pv[0][1]);
      t0.u4[1] = pack2bf(pv[0][2], pv[0][3]);
      t0.u4[2] = pack2bf(pv[1][0], pv[1][1]);
      t0.u4[3] = pack2bf(pv[1][2], pv[1][3]);
      t1.u4[0] = pack2bf(pv[2][0], pv[2][1]);
      t1.u4[1] = pack2bf(pv[2][2], pv[2][3]);
      t1.u4[2] = pack2bf(pv[3][0], pv[3][1]);
      t1.u4[3] = pack2bf(pv[3][2], pv[3][3]);
      ap[g][0] = t0.v;
      ap[g][1] = t1.v;
    }

    // O += P.V
#pragma unroll
    for (int hh = 0; hh < 2; ++hh)
#pragma unroll
      for (int di = 0; di < 4; ++di) {
        bf16x8 bv = vfr[hh][di];
#pragma unroll
        for (int g = 0; g < 2; ++g)
          accO[g][di] = __builtin_amdgcn_mfma_f32_16x16x32_bf16(ap[g][hh], bv,
                                                               accO[g][di], 0, 0, 0);
      }

    // rotate K pipeline
#pragma unroll
    for (int m = 0; m < 4; ++m)
#pragma unroll
      for (int hh = 0; hh < 2; ++hh)
        kcur[m][hh] = knx[m][hh];
  }

  // ---- exact parity combine (per-lane values) ----
  if (par) {
    float* cb = CB[w & 1][lane];
#pragma unroll
    for (int g = 0; g < 2; ++g)
#pragma unroll
      for (int di = 0; di < 4; ++di)
#pragma unroll
        for (int r = 0; r < 4; ++r)
          cb[g * 16 + di * 4 + r] = accO[g][di][r];
    cb[32] = lrow[0];
    cb[33] = lrow[1];
  }
  __syncthreads();
  if (!par) {
    const float* cb = CB[w & 1][lane];
#pragma unroll
    for (int g = 0; g < 2; ++g)
#pragma unroll
      for (int di = 0; di < 4; ++di)
#pragma unroll
        for (int r = 0; r < 4; ++r)
          accO[g][di][r] += cb[g * 16 + di * 4 + r];
    lrow[0] += cb[32];
    lrow[1] += cb[33];
    // cross-quad l reduction (deferred from the tile loop)
#pragma unroll
    for (int g = 0; g < 2; ++g) {
      lrow[g] += __shfl_xor(lrow[g], 16);
      lrow[g] += __shfl_xor(lrow[g], 32);
    }

#pragma unroll
    for (int g = 0; g < 2; ++g)
#pragma unroll
      for (int r = 0; r < 4; ++r) {
        const float lv = __shfl(lrow[g], quad * 4 + r);
        const float inv = 1.f / lv;
        const int q = q0 + g * 16 + quad * 4 + r;
        u16* op = out + (size_t)(b * 2048 + q) * 1024 + h * 64 + l15;
#pragma unroll
        for (int di = 0; di < 4; ++di)
          op[di * 16] = f2bf(accO[g][di][r] * inv);
      }
  }
}

// ---------------------------------------------------------------------------
extern "C" void kernel_launch(void* const* d_in, const int* in_sizes, int n_in,
                              void* d_out, int out_size, void* d_ws, size_t ws_size,
                              hipStream_t stream) {
  const float* x     = (const float*)d_in[0];
  const float* Wqkv  = (const float*)d_in[1];
  const float* bqkv  = (const float*)d_in[2];
  const float* Wproj = (const float*)d_in[3];
  const float* bproj = (const float*)d_in[4];
  float* out = (float*)d_out;

  char* ws = (char*)d_ws;
  u16* xb     = (u16*)(ws);                 //  8 MB  x bf16 [4096,1024]
  u16* wqkvT  = (u16*)(ws + 8388608);       //  6 MB  Wqkv^T bf16 [3072,1024]
  u16* wprojT = (u16*)(ws + 14680064);      //  2 MB  Wproj^T bf16 [1024,1024]
  u16* qb     = (u16*)(ws + 16777216);      //  8 MB  Q bf16 [4096,1024] (pre-scaled)
  u16* KF     = (u16*)(ws + 25165824);      //  8 MB  K fragment-order
  u16* VF     = (u16*)(ws + 33554432);      //  8 MB  V fragment-order (k-perm)
  u16* att    = (u16*)(ws + 41943040);      //  8 MB  attn out bf16 [4096,1024]

  constexpr float cs = 0.18033688011f;      // log2(e)/8

  prep<<<8192, 256, 0, stream>>>(x, xb, Wqkv, wqkvT, Wproj, wprojT);

  gemm_qkv<<<dim3(192), 512, 0, stream>>>(xb, wqkvT, bqkv, qb, KF, VF, cs);

  attn_bal<<<dim3(32, 32), 256, 0, stream>>>(qb, KF, VF, att);

  gemm_proj<<<dim3(32, 16), 256, 0, stream>>>(att, wprojT, bproj, out);
}

// Round 2
// 168.091 us; speedup vs baseline: 1.1041x; 1.0507x over previous
//
#include <hip/hip_runtime.h>
#include <hip/hip_bf16.h>
#include <cstdint>

// ---------------------------------------------------------------------------
// CausalSelfAttention: x@Wqkv+b -> heads -> causal flash attn -> @Wproj+b
// B=2 T=2048 C=1024 H=16 Dh=64.
// R12: gemm_qkv = 256x192 tile, 3-phase pipeline, FULL 256-block coverage.
//  - R11 post-mortem: 256x256 -> 192 blocks left 64 CUs idle (13% occupancy);
//    swizzle verified (bank conflicts 3.1M->0) but coverage ate the gain.
//  - LDS: 2 bufs x 7 chunks of [64][64] u16 (A=4 chunks, B=3) = 112 KiB.
//  - Per K-tile (BK=64): 3 phases x 16 MFMA/wave (wave tile 128x48, acc[8][3]).
//    p0: ds a_lo+b0,b1 (12 rd) | stage A2A3(j+1)->other | MFMA mi0-3 x ni0,1
//    p1: ds a_hi+b2   (10 rd) | stage B0B1(j+2)->cur   | MFMA mi0-3xni2 + mi4-7xni0
//    p2:                      | stage B2A0A1(j+2)->cur | MFMA mi4-7 x ni1,2 ; vmcnt(5)
//  - Overwrite safety: chunk last READ in phase p is overwritten no earlier
//    than p+1 (every phase ends lgkm0-before-MFMA + barrier => reads drained).
//  - vmcnt(5) at p2: leaves exactly {B0B1,B2A0A1}(j+2) in flight; drains
//    A2A3(j+1) and older => buf(j+1) fully landed before p0(j+1) reads it.
//  - XCD map: 256 blocks, xcd=bid&7 -> 4x8 tile region per XCD.
// R12b: attn_bal block remap for KV L2 residency: each XCD owns 4 bh
//  (2 MB KF+VF < 4 MiB L2, reused 32x); consecutive blocks walk u for one bh.
// HARD-WON NOTES (attn, unchanged):
//  - R7: __launch_bounds__(256,4) forced VGPR=64 -> 380MB scratch spills.
//  - R8: V-frag loads after softmax doubled per-tile exposed latency.
//  - R10: K-frags pipelined one tile ahead; ps tree-summed; l-reduction
//    deferred to epilogue.
// ---------------------------------------------------------------------------

using u16 = unsigned short;
using u32 = unsigned int;

typedef __bf16 bf16x8 __attribute__((ext_vector_type(8)));
typedef float f32x4 __attribute__((ext_vector_type(4)));

#define AS1 __attribute__((address_space(1)))
#define AS3 __attribute__((address_space(3)))

__device__ __forceinline__ u16 f2bf(float f) {
  u32 u = __float_as_uint(f);
  u += 0x7fffu + ((u >> 16) & 1u);   // RTNE
  return (u16)(u >> 16);
}
// pack two positive floats -> two bf16
__device__ __forceinline__ u32 pack2bf(float a, float b) {
  u32 ua = __float_as_uint(a) + 0x8000u;
  u32 ub = __float_as_uint(b) + 0x8000u;
  return (ua >> 16) | (ub & 0xffff0000u);
}

// ---------------- prep: cvt x->bf16 (blocks 0..4095) + W transposes ---------
__global__ __launch_bounds__(256) void prep(const float* __restrict__ x,
                                            u16* __restrict__ xb,
                                            const float* __restrict__ W0,
                                            u16* __restrict__ T0,
                                            const float* __restrict__ W1,
                                            u16* __restrict__ T1) {
  const int bx = blockIdx.x;
  const int tid = threadIdx.x;
  if (bx < 4096) {
    const int i = bx * 256 + tid;
    float4 v = ((const float4*)x)[i];
    ushort4 o;
    o.x = f2bf(v.x); o.y = f2bf(v.y); o.z = f2bf(v.z); o.w = f2bf(v.w);
    ((ushort4*)xb)[i] = o;
    return;
  }
  __shared__ float t[32][33];
  const int idx = bx - 4096;          // 128 n-tiles x 32 k-tiles
  const int bxx = idx & 127, by = idx >> 7;
  const float* W; u16* Wt; int N, n0;
  if (bxx < 96) { W = W0; Wt = T0; N = 3072; n0 = bxx * 32; }
  else          { W = W1; Wt = T1; N = 1024; n0 = (bxx - 96) * 32; }
  const int k0 = by * 32;
  const int tx = tid & 31, ty = tid >> 5;
#pragma unroll
  for (int i = 0; i < 4; ++i)
    t[ty + i * 8][tx] = W[(size_t)(k0 + ty + i * 8) * N + n0 + tx];
  __syncthreads();
#pragma unroll
  for (int i = 0; i < 4; ++i)
    Wt[(size_t)(n0 + ty + i * 8) * 1024 + k0 + tx] = f2bf(t[tx][ty + i * 8]);
}

// ---------------- QKV GEMM: 256x192 3-phase pipelined -----------------------
// n<1024: Q (scaled by cs) -> qb[4096][1024]
// 1024<=n<2048: K -> KF fragment order [bh][kt][m][hh][lane][8]
// n>=2048:     V -> VF fragment order [bh][kt][hh][di][lane][8] (k-permuted)
#define MFMA16 __builtin_amdgcn_mfma_f32_16x16x32_bf16

__global__ __launch_bounds__(512, 2) void gemm_qkv(const u16* __restrict__ A,
                                                   const u16* __restrict__ Bt,
                                                   const float* __restrict__ bias,
                                                   u16* __restrict__ qb,
                                                   u16* __restrict__ KF,
                                                   u16* __restrict__ VF,
                                                   float sc_val) {
  constexpr int NT = 16;                    // K=1024 / BK=64
  constexpr int BUFO = 7 * 4096;            // u16 per buffer (7 chunks)
  __shared__ __align__(16) u16 sm[2 * BUFO];  // 112 KiB

  const int tid  = threadIdx.x;
  const int lane = tid & 63;
  const int w    = tid >> 6;          // 0..7
  const int quad = lane >> 4;
  const int l15  = lane & 15;

  // block -> tile: XCD-bijective (256 blocks = 8 XCD x 32), 4x8 region/XCD
  const int bid = blockIdx.x;
  const int xcd = bid & 7, c = bid >> 3;         // c 0..31
  const int mt = (xcd >> 1) * 4 + (c & 3);       // 0..15
  const int nt = (xcd & 1) * 8 + (c >> 2);       // 0..15
  const int bm = mt * 256, bn = nt * 192;

  const int wr = (w >> 2) * 128;      // wave rows (0/128)
  const int wc = (w & 3) * 48;        // wave cols (0/48/96/144)

  // ---- staging: thread writes 16B linearly at chunk + tid*16.
  // LDS row = tid>>3, granule = tid&7; source granule = (tid&7)^(row&7).
  const int srow = tid >> 3;
  const int scol = (((tid & 7) ^ ((tid >> 3) & 7)) << 3);

#define STAGEA(ch, ktile, bufo)                                                 \
  __builtin_amdgcn_global_load_lds(                                             \
      (AS1 const void*)(A + (size_t)(bm + (ch) * 64 + srow) * 1024 +            \
                        ((ktile) << 6) + scol),                                 \
      (AS3 void*)(sm + (bufo) + (ch) * 4096 + tid * 8), 16, 0, 0)
#define STAGEB(ch, ktile, bufo)                                                 \
  __builtin_amdgcn_global_load_lds(                                             \
      (AS1 const void*)(Bt + (size_t)(bn + (ch) * 64 + srow) * 1024 +           \
                        ((ktile) << 6) + scol),                                 \
      (AS3 void*)(sm + (bufo) + (4 + (ch)) * 4096 + tid * 8), 16, 0, 0)

  // ---- ds-read bases (swizzled granule; row&7 == l15&7 everywhere)
  const int ca = (w >> 2) * 2;        // A chunk base: 0 or 2
  int abase_lo[4], abase_hi[4], bbase[3];
#pragma unroll
  for (int mi = 0; mi < 4; ++mi) {
    abase_lo[mi] = (ca + 0) * 4096 + (mi * 16 + l15) * 64;
    abase_hi[mi] = (ca + 1) * 4096 + (mi * 16 + l15) * 64;
  }
#pragma unroll
  for (int ni = 0; ni < 3; ++ni) {
    const int rb = wc + ni * 16 + l15;            // 0..191
    bbase[ni] = (4 + (rb >> 6)) * 4096 + (rb & 63) * 64;
  }
  const int sw0 = ((quad ^ (l15 & 7)) << 3);
  const int sw1 = sw0 ^ 32;

  // ---- prologue: kt0 all 7 -> buf0; kt1 B0B1,B2A0A1 -> buf1
  STAGEA(0, 0, 0); STAGEA(1, 0, 0); STAGEA(2, 0, 0); STAGEA(3, 0, 0);
  STAGEB(0, 0, 0); STAGEB(1, 0, 0); STAGEB(2, 0, 0);
  STAGEB(0, 1, BUFO); STAGEB(1, 1, BUFO);
  STAGEB(2, 1, BUFO); STAGEA(0, 1, BUFO); STAGEA(1, 1, BUFO);
  asm volatile("s_waitcnt vmcnt(5)" ::: "memory");  // kt0 landed; kt1's 5 fly
  __builtin_amdgcn_s_barrier();

  f32x4 acc[8][3] = {};
  bf16x8 alo[4][2], ahi[4][2], b[3][2];

#pragma unroll 2
  for (int j = 0; j < NT; ++j) {
    const int bo  = (j & 1) * BUFO;
    const int nbo = bo ^ BUFO;
    const u16* smb = sm + bo;

    // ---------- phase 0: ds a_lo + b0,b1; stage A2A3(j+1); MFMA mi0-3 x ni0,1
#pragma unroll
    for (int mi = 0; mi < 4; ++mi) {
      alo[mi][0] = *(const bf16x8*)(smb + abase_lo[mi] + sw0);
      alo[mi][1] = *(const bf16x8*)(smb + abase_lo[mi] + sw1);
    }
#pragma unroll
    for (int ni = 0; ni < 2; ++ni) {
      b[ni][0] = *(const bf16x8*)(smb + bbase[ni] + sw0);
      b[ni][1] = *(const bf16x8*)(smb + bbase[ni] + sw1);
    }
    if (j + 1 < NT) { STAGEA(2, j + 1, nbo); STAGEA(3, j + 1, nbo); }
    __builtin_amdgcn_s_barrier();
    asm volatile("s_waitcnt lgkmcnt(0)" ::: "memory");
    __builtin_amdgcn_s_setprio(1);
#pragma unroll
    for (int mi = 0; mi < 4; ++mi)
#pragma unroll
      for (int ni = 0; ni < 2; ++ni) {
        acc[mi][ni] = MFMA16(alo[mi][0], b[ni][0], acc[mi][ni], 0, 0, 0);
        acc[mi][ni] = MFMA16(alo[mi][1], b[ni][1], acc[mi][ni], 0, 0, 0);
      }
    __builtin_amdgcn_s_setprio(0);
    __builtin_amdgcn_s_barrier();

    // ---------- phase 1: ds a_hi + b2; stage B0B1(j+2); MFMA mi0-3xni2 + mi4-7xni0
#pragma unroll
    for (int mi = 0; mi < 4; ++mi) {
      ahi[mi][0] = *(const bf16x8*)(smb + abase_hi[mi] + sw0);
      ahi[mi][1] = *(const bf16x8*)(smb + abase_hi[mi] + sw1);
    }
    b[2][0] = *(const bf16x8*)(smb + bbase[2] + sw0);
    b[2][1] = *(const bf16x8*)(smb + bbase[2] + sw1);
    if (j + 2 < NT) { STAGEB(0, j + 2, bo); STAGEB(1, j + 2, bo); }
    __builtin_amdgcn_s_barrier();
    asm volatile("s_waitcnt lgkmcnt(0)" ::: "memory");
    __builtin_amdgcn_s_setprio(1);
#pragma unroll
    for (int mi = 0; mi < 4; ++mi) {
      acc[mi][2] = MFMA16(alo[mi][0], b[2][0], acc[mi][2], 0, 0, 0);
      acc[mi][2] = MFMA16(alo[mi][1], b[2][1], acc[mi][2], 0, 0, 0);
      acc[4 + mi][0] = MFMA16(ahi[mi][0], b[0][0], acc[4 + mi][0], 0, 0, 0);
      acc[4 + mi][0] = MFMA16(ahi[mi][1], b[0][1], acc[4 + mi][0], 0, 0, 0);
    }
    __builtin_amdgcn_s_setprio(0);
    __builtin_amdgcn_s_barrier();

    // ---------- phase 2: stage B2,A0,A1(j+2); MFMA mi4-7 x ni1,2; vmcnt(5)
    if (j + 2 < NT) { STAGEB(2, j + 2, bo); STAGEA(0, j + 2, bo); STAGEA(1, j + 2, bo); }
    __builtin_amdgcn_s_barrier();
    __builtin_amdgcn_s_setprio(1);
#pragma unroll
    for (int mi = 0; mi < 4; ++mi)
#pragma unroll
      for (int ni = 1; ni < 3; ++ni) {
        acc[4 + mi][ni] = MFMA16(ahi[mi][0], b[ni][0], acc[4 + mi][ni], 0, 0, 0);
        acc[4 + mi][ni] = MFMA16(ahi[mi][1], b[ni][1], acc[4 + mi][ni], 0, 0, 0);
      }
    __builtin_amdgcn_s_setprio(0);
    if (j + 2 < NT)
      asm volatile("s_waitcnt vmcnt(5)" ::: "memory"); // drains A2A3(j+1)+older
    else
      asm volatile("s_waitcnt vmcnt(0)" ::: "memory"); // tail drain
    __builtin_amdgcn_s_barrier();
  }
#undef STAGEA
#undef STAGEB

  // ---- epilogue: per-ni region branch (192-wide blocks straddle Q/K/V) ----
  const int crow0 = bm + wr + (quad << 2);
  const int ccol0 = bn + wc + l15;
#pragma unroll
  for (int ni = 0; ni < 3; ++ni) {
    const int n = ccol0 + ni * 16;
    const float bv = bias[n];
    if (n < 1024) {                     // ---- Q (scaled) ----
#pragma unroll
      for (int mi = 0; mi < 8; ++mi) {
        const int m0 = crow0 + mi * 16;
#pragma unroll
        for (int r = 0; r < 4; ++r)
          qb[(size_t)(m0 + r) * 1024 + n] = f2bf((acc[mi][ni][r] + bv) * sc_val);
      }
    } else if (n < 2048) {              // ---- K fragment order ----
      const int hk = (n - 1024) >> 6;
      const int d  = (n - 1024) & 63;
      const int hh = d >> 5, qd = (d >> 3) & 3, jj = d & 7;
#pragma unroll
      for (int mi = 0; mi < 8; ++mi) {
#pragma unroll
        for (int r = 0; r < 4; ++r) {
          const int t  = crow0 + mi * 16 + r;
          const int bb = t >> 11, tt = t & 2047;
          const int kt = tt >> 6, mm = (tt >> 4) & 3, l = tt & 15;
          KF[((size_t)((bb * 16 + hk) * 32 + kt) * 8 + mm * 2 + hh) * 512 +
             (qd * 16 + l) * 8 + jj] = f2bf(acc[mi][ni][r] + bv);
        }
      }
    } else {                            // ---- V fragment order (k-perm) ----
      const int hv = (n - 2048) >> 6;
      const int d  = (n - 2048) & 63;
      const int di = d >> 4, l = d & 15;
#pragma unroll
      for (int mi = 0; mi < 8; ++mi) {
#pragma unroll
        for (int r = 0; r < 4; ++r) {
          const int t  = crow0 + mi * 16 + r;
          const int bb = t >> 11, tt = t & 2047;
          const int kt = tt >> 6, to = tt & 63;
          const int mq = to >> 4, qd2 = (to >> 2) & 3, rr = to & 3;
          const int hh = mq >> 1, jj = (mq & 1) * 4 + rr;
          VF[((size_t)((bb * 16 + hv) * 32 + kt) * 8 + hh * 4 + di) * 512 +
             (qd2 * 16 + l) * 8 + jj] = f2bf(acc[mi][ni][r] + bv);
        }
      }
    }
  }
}

// ---------------- Proj GEMM: 128x64 tile, fp32 out --------------------------
__global__ __launch_bounds__(256) void gemm_proj(const u16* __restrict__ A,
                                                 const u16* __restrict__ Bt,
                                                 const float* __restrict__ bias,
                                                 float* __restrict__ C) {
  constexpr int BM = 128, BN = 64, BK = 32;
  constexpr int K = 1024, N = 1024;
  __shared__ __align__(16) u16 lA[BM * BK];
  __shared__ __align__(16) u16 lB[BN * BK];
  const int tid  = threadIdx.x;
  const int lane = tid & 63;
  const int wave = tid >> 6;
  const int bm = blockIdx.x * BM;
  const int bn = blockIdx.y * BN;
  const int wr = wave * 32;

  f32x4 acc[2][4] = {};

  const int f0 = (wave << 10) + (lane << 4);
  const int f1 = f0 + 4096;
  const int ar0 = f0 >> 6, ac0 = (f0 & 63) >> 1;
  const int ar1 = f1 >> 6, ac1 = (f1 & 63) >> 1;

  const int arow = wr + (lane & 15);
  const int brow = (lane & 15);
  const int kk   = (lane >> 4) << 3;

  for (int k0 = 0; k0 < K; k0 += BK) {
    __builtin_amdgcn_global_load_lds((AS1 const void*)(A + (size_t)(bm + ar0) * K + k0 + ac0),
                                     (AS3 void*)(lA + (wave << 9)), 16, 0, 0);
    __builtin_amdgcn_global_load_lds((AS1 const void*)(A + (size_t)(bm + ar1) * K + k0 + ac1),
                                     (AS3 void*)(lA + ((wave + 4) << 9)), 16, 0, 0);
    __builtin_amdgcn_global_load_lds((AS1 const void*)(Bt + (size_t)(bn + ar0) * K + k0 + ac0),
                                     (AS3 void*)(lB + (wave << 9)), 16, 0, 0);
    __syncthreads();

    bf16x8 af[2], bfr[4];
#pragma unroll
    for (int mi = 0; mi < 2; ++mi)
      af[mi] = *(const bf16x8*)&lA[(arow + mi * 16) * BK + kk];
#pragma unroll
    for (int ni = 0; ni < 4; ++ni)
      bfr[ni] = *(const bf16x8*)&lB[(brow + ni * 16) * BK + kk];
#pragma unroll
    for (int mi = 0; mi < 2; ++mi)
#pragma unroll
      for (int ni = 0; ni < 4; ++ni)
        acc[mi][ni] = __builtin_amdgcn_mfma_f32_16x16x32_bf16(af[mi], bfr[ni],
                                                              acc[mi][ni], 0, 0, 0);
    __syncthreads();
  }

  const int crow0 = bm + wr + ((lane >> 4) << 2);
  const int ccol0 = bn + (lane & 15);
#pragma unroll
  for (int ni = 0; ni < 4; ++ni) {
    const int n = ccol0 + ni * 16;
    const float bv = bias[n];
#pragma unroll
    for (int mi = 0; mi < 2; ++mi) {
      const int m0 = crow0 + mi * 16;
#pragma unroll
      for (int r = 0; r < 4; ++r)
        C[(size_t)(m0 + r) * N + n] = acc[mi][ni][r] + bv;
    }
  }
}

// ---------------- balanced pipelined MFMA flash attention -------------------
// grid 1024 flat; remapped so XCD x (= f&7, round-robin dispatch) owns
// bh in {x, x+8, x+16, x+24}: KF+VF for 4 bh = 2 MB, resident in that XCD's
// 4 MiB L2 and reused by 32 consecutive u-blocks.  block 256 = 4 waves.
// wave w: g32 = (w&1) ? 63-u : u, par = w>>1; kt = par, par+2, ... <= ktmax.
__global__ __launch_bounds__(256) void attn_bal(const u16* __restrict__ qb,
                                                const u16* __restrict__ KF,
                                                const u16* __restrict__ VF,
                                                u16* __restrict__ out) {
  const int f  = blockIdx.x;
  const int u  = (f >> 3) & 31;
  const int bh = (f & 7) | ((f >> 8) << 3);
  const int b = bh >> 4, h = bh & 15;
  const int tid = threadIdx.x;
  const int lane = tid & 63;
  const int w    = tid >> 6;
  const int quad = lane >> 4;
  const int l15  = lane & 15;
  const int g32 = (w & 1) ? (63 - u) : u;
  const int par = w >> 1;
  const int q0 = g32 * 32;
  const int ktmax = g32 >> 1;

  __shared__ float CB[2][64][35];     // [unit][lane][32 accO + 2 lsum]

  // Q B-frags, held all kernel
  const u16* qbase = qb + (size_t)b * 2048 * 1024 + h * 64;
  bf16x8 qf[2][2];
#pragma unroll
  for (int g = 0; g < 2; ++g)
#pragma unroll
    for (int hh = 0; hh < 2; ++hh)
      qf[g][hh] = *(const bf16x8*)(qbase + (size_t)(q0 + g * 16 + l15) * 1024 +
                                   hh * 32 + quad * 8);

  const size_t fb = (size_t)bh * 32 * 4096 + lane * 8;
  const u16* kfb = KF + fb;
  const u16* vfb = VF + fb;

  f32x4 accO[2][4] = {};              // [g][di]: q=quad*4+r, d=di*16+l15
  float lrow[2] = {0.f, 0.f};         // PER-LANE partials; reduced in epilogue

  // prologue: K-frags for first tile
  bf16x8 kcur[4][2];
  {
    const u16* kp = kfb + (size_t)par * 4096;
#pragma unroll
    for (int m = 0; m < 4; ++m)
#pragma unroll
      for (int hh = 0; hh < 2; ++hh)
        kcur[m][hh] = *(const bf16x8*)(kp + (m * 2 + hh) * 512);
  }

  for (int kt = par; kt <= ktmax; kt += 2) {
    // V-frags for current tile at top
    const u16* vp = vfb + (size_t)kt * 4096;
    bf16x8 vfr[2][4];
#pragma unroll
    for (int hh = 0; hh < 2; ++hh)
#pragma unroll
      for (int di = 0; di < 4; ++di)
        vfr[hh][di] = *(const bf16x8*)(vp + (hh * 4 + di) * 512);
    // K-frags for tile kt+2 (clamped) -- used NEXT iteration
    const int ktn = (kt + 2 <= ktmax) ? kt + 2 : ktmax;
    const u16* kpn = kfb + (size_t)ktn * 4096;
    bf16x8 knx[4][2];
#pragma unroll
    for (int m = 0; m < 4; ++m)
#pragma unroll
      for (int hh = 0; hh < 2; ++hh)
        knx[m][hh] = *(const bf16x8*)(kpn + (m * 2 + hh) * 512);

    const bool diag = (kt == ktmax);
    bf16x8 ap[2][2];
#pragma unroll
    for (int g = 0; g < 2; ++g) {
      f32x4 sT[4] = {};
#pragma unroll
      for (int m = 0; m < 4; ++m) {
        sT[m] = __builtin_amdgcn_mfma_f32_16x16x32_bf16(kcur[m][0], qf[g][0], sT[m], 0, 0, 0);
        sT[m] = __builtin_amdgcn_mfma_f32_16x16x32_bf16(kcur[m][1], qf[g][1], sT[m], 0, 0, 0);
      }
      float pv[4][4];
      if (diag) {                      // only the last tile pays mask ops
        const int qgl = q0 + g * 16 + l15;
#pragma unroll
        for (int m = 0; m < 4; ++m)
#pragma unroll
          for (int r = 0; r < 4; ++r) {
            const bool msk = (kt * 64 + m * 16 + quad * 4 + r) > qgl;
            pv[m][r] = msk ? 0.f : __builtin_amdgcn_exp2f(sT[m][r]);
          }
      } else {
#pragma unroll
        for (int m = 0; m < 4; ++m)
#pragma unroll
          for (int r = 0; r < 4; ++r)
            pv[m][r] = __builtin_amdgcn_exp2f(sT[m][r]);
      }
      // tree sum (fp adds not reassociable by compiler -- do it manually)
      const float s0 = (pv[0][0] + pv[0][1]) + (pv[0][2] + pv[0][3]);
      const float s1 = (pv[1][0] + pv[1][1]) + (pv[1][2] + pv[1][3]);
      const float s2 = (pv[2][0] + pv[2][1]) + (pv[2][2] + pv[2][3]);
      const float s3 = (pv[3][0] + pv[3][1]) + (pv[3][2] + pv[3][3]);
      lrow[g] += (s0 + s1) + (s2 + s3);

      union { u32 u4[4]; bf16x8 v; } t0, t1;
      t0.u4[0] = pack2bf(pv[0][0], pv[0][1]);
      t0.u4[1] = pack2bf(pv[0][2], pv[0][3]);
      t0.u4[2] = pack2bf(pv[1][0], pv[1][1]);
      t0.u4[3] = pack2bf(pv[1][2], pv[1][3]);
      t1.u4[0] = pack2bf(pv[2][0], pv[2][1]);
      t1.u4[1] = pack2bf(pv[2][2], pv[2][3]);
      t1.u4[2] = pack2bf(pv[3][0], pv[3][1]);
      t1.u4[3] = pack2bf(pv[3][2], pv[3][3]);
      ap[g][0] = t0.v;
      ap[g][1] = t1.v;
    }

    // O += P.V
#pragma unroll
    for (int hh = 0; hh < 2; ++hh)
#pragma unroll
      for (int di = 0; di < 4; ++di) {
        bf16x8 bv = vfr[hh][di];
#pragma unroll
        for (int g = 0; g < 2; ++g)
          accO[g][di] = __builtin_amdgcn_mfma_f32_16x16x32_bf16(ap[g][hh], bv,
                                                               accO[g][di], 0, 0, 0);
      }

    // rotate K pipeline
#pragma unroll
    for (int m = 0; m < 4; ++m)
#pragma unroll
      for (int hh = 0; hh < 2; ++hh)
        kcur[m][hh] = knx[m][hh];
  }

  // ---- exact parity combine (per-lane values) ----
  if (par) {
    float* cb = CB[w & 1][lane];
#pragma unroll
    for (int g = 0; g < 2; ++g)
#pragma unroll
      for (int di = 0; di < 4; ++di)
#pragma unroll
        for (int r = 0; r < 4; ++r)
          cb[g * 16 + di * 4 + r] = accO[g][di][r];
    cb[32] = lrow[0];
    cb[33] = lrow[1];
  }
  __syncthreads();
  if (!par) {
    const float* cb = CB[w & 1][lane];
#pragma unroll
    for (int g = 0; g < 2; ++g)
#pragma unroll
      for (int di = 0; di < 4; ++di)
#pragma unroll
        for (int r = 0; r < 4; ++r)
          accO[g][di][r] += cb[g * 16 + di * 4 + r];
    lrow[0] += cb[32];
    lrow[1] += cb[33];
    // cross-quad l reduction (deferred from the tile loop)
#pragma unroll
    for (int g = 0; g < 2; ++g) {
      lrow[g] += __shfl_xor(lrow[g], 16);
      lrow[g] += __shfl_xor(lrow[g], 32);
    }

#pragma unroll
    for (int g = 0; g < 2; ++g)
#pragma unroll
      for (int r = 0; r < 4; ++r) {
        const float lv = __shfl(lrow[g], quad * 4 + r);
        const float inv = 1.f / lv;
        const int q = q0 + g * 16 + quad * 4 + r;
        u16* op = out + (size_t)(b * 2048 + q) * 1024 + h * 64 + l15;
#pragma unroll
        for (int di = 0; di < 4; ++di)
          op[di * 16] = f2bf(accO[g][di][r] * inv);
      }
  }
}

// ---------------------------------------------------------------------------
extern "C" void kernel_launch(void* const* d_in, const int* in_sizes, int n_in,
                              void* d_out, int out_size, void* d_ws, size_t ws_size,
                              hipStream_t stream) {
  const float* x     = (const float*)d_in[0];
  const float* Wqkv  = (const float*)d_in[1];
  const float* bqkv  = (const float*)d_in[2];
  const float* Wproj = (const float*)d_in[3];
  const float* bproj = (const float*)d_in[4];
  float* out = (float*)d_out;

  char* ws = (char*)d_ws;
  u16* xb     = (u16*)(ws);                 //  8 MB  x bf16 [4096,1024]
  u16* wqkvT  = (u16*)(ws + 8388608);       //  6 MB  Wqkv^T bf16 [3072,1024]
  u16* wprojT = (u16*)(ws + 14680064);      //  2 MB  Wproj^T bf16 [1024,1024]
  u16* qb     = (u16*)(ws + 16777216);      //  8 MB  Q bf16 [4096,1024] (pre-scaled)
  u16* KF     = (u16*)(ws + 25165824);      //  8 MB  K fragment-order
  u16* VF     = (u16*)(ws + 33554432);      //  8 MB  V fragment-order (k-perm)
  u16* att    = (u16*)(ws + 41943040);      //  8 MB  attn out bf16 [4096,1024]

  constexpr float cs = 0.18033688011f;      // log2(e)/8

  prep<<<8192, 256, 0, stream>>>(x, xb, Wqkv, wqkvT, Wproj, wprojT);

  gemm_qkv<<<dim3(256), 512, 0, stream>>>(xb, wqkvT, bqkv, qb, KF, VF, cs);

  attn_bal<<<dim3(1024), 256, 0, stream>>>(qb, KF, VF, att);

  gemm_proj<<<dim3(32, 16), 256, 0, stream>>>(att, wprojT, bproj, out);
}